// Round 10
// baseline (315.398 us; speedup 1.0000x reference)
//
#include <hip/hip_runtime.h>

#define TSTEPS 512
#define BPB    8                  // batches per block, rows {0,1,4,5,8,9,12,13}
#define ROWB   256                // bytes per A row (96 k-slots used)
#define ABYTES (16 * ROWB)        // 4096
#define LOG2E  1.44269504088896340736f

typedef short bf16x8 __attribute__((ext_vector_type(8)));
typedef float f32x4  __attribute__((ext_vector_type(4)));

__device__ __forceinline__ unsigned int f2bf(float f) {   // RTN-even
    unsigned int u = __builtin_bit_cast(unsigned int, f);
    return (u + 0x7FFFu + ((u >> 16) & 1u)) >> 16;
}
__device__ __forceinline__ float bf2f(unsigned int us) {
    return __builtin_bit_cast(float, us << 16);
}
__device__ __forceinline__ unsigned int split_pack(float f) {  // hi | lo<<16
    unsigned int hi = f2bf(f);
    unsigned int lo = f2bf(f - bf2f(hi));
    return hi | (lo << 16);
}
__device__ __forceinline__ float rcp1p(float e) {   // 1/(1+e)
    return __builtin_amdgcn_rcpf(1.0f + e);
}

// Round-8 math with log2e folded into B: for gates i,f,o the B columns carry
// factor -log2e  -> sigmoid(raw) = rcp(1+exp2(acc));
// for gate g factor 2*log2e     -> tanh(raw) = fma(-2, rcp(1+exp2(acc)), 1).
// NEW structure: 8 waves/block (512 thr), wave (p = w>>2, c = w&3) computes
// gate-pair {2p, 2p+1} for h-chunk c: 2 N-tiles x 3 K-steps = 6 MFMA (per
// CU-step MFMA pipe halves vs round 8). Raw pre-activations for the other
// r-row are exchanged between wave-pairs (p <-> 1-p) through a 4KB f32 LDS
// buffer; wave p then runs the nonlinearity for batches r=p only -> trans
// stays fully lane-packed. Two barriers/step. grid 256 -> 1 block/CU,
// 2 waves/SIMD.
__global__ __launch_bounds__(512, 2) void lstm_mfma8_kernel(
    const float* __restrict__ x,      // [B, T, 4]
    const float* __restrict__ W_ih,   // [256, 4]
    const float* __restrict__ W_hh,   // [256, 49]
    const float* __restrict__ b_ih,   // [256]
    const float* __restrict__ b_hh,   // [256]
    const float* __restrict__ W_hr,   // [49, 64]
    const float* __restrict__ W_out,  // [49, 49]
    const float* __restrict__ b_out,  // [49]
    float* __restrict__ out)          // [B, 49]
{
    const int tid = threadIdx.x;
    const int w   = tid >> 6;         // wave 0..7
    const int p   = w >> 2;           // gate-pair: 0 -> (i,f), 1 -> (g,o)
    const int c   = w & 3;            // h-chunk (16 cols)
    const int l   = tid & 63;
    const int g4  = l >> 4;
    const int ln  = l & 15;
    const int b0  = blockIdx.x * BPB;

    __shared__ __align__(128) unsigned char Abuf[2 * ABYTES];  // hf/x dbuf, 8KB
    __shared__ float ex[2 * 4 * 2 * 64];                       // gate exchange, 4KB
    __shared__ __align__(16) float hf32[BPB][64];
    __shared__ float hproj[BPB][52];

    // ---------------- prologue ----------------
    for (int i = tid; i < (2 * ABYTES) / 4; i += 512)
        ((unsigned int*)Abuf)[i] = 0u;

    // M[k][n] = sum_q W_hr[q][k] * W_hh[n][q] for this wave's 2 tiles
    float Msum[2][16];
    #pragma unroll
    for (int i = 0; i < 2; ++i)
        #pragma unroll
        for (int k = 0; k < 16; ++k) Msum[i][k] = 0.0f;

    for (int q = 0; q < 49; ++q) {
        float wr[16];
        #pragma unroll
        for (int s = 0; s < 2; ++s)
            #pragma unroll
            for (int j = 0; j < 8; ++j)
                wr[s * 8 + j] = W_hr[q * 64 + s * 32 + g4 * 8 + j];
        #pragma unroll
        for (int i = 0; i < 2; ++i) {
            const int n = (2 * p + i) * 64 + c * 16 + ln;
            const float whh = W_hh[n * 49 + q];
            #pragma unroll
            for (int k = 0; k < 16; ++k) Msum[i][k] += whh * wr[k];
        }
    }

    // Resident B fragments with log2e factors folded in
    bf16x8 Bf[2][3];
    union U { unsigned int d[4]; bf16x8 v; };
    #pragma unroll
    for (int i = 0; i < 2; ++i) {
        const int t4 = 2 * p + i;
        const float fac = (t4 == 2) ? 2.0f * LOG2E : -LOG2E;
        #pragma unroll
        for (int s = 0; s < 2; ++s) {
            U u;
            #pragma unroll
            for (int jj = 0; jj < 4; ++jj) {
                const unsigned int e0 = f2bf(fac * Msum[i][s * 8 + 2 * jj]);
                const unsigned int e1 = f2bf(fac * Msum[i][s * 8 + 2 * jj + 1]);
                u.d[jj] = e0 | (e1 << 16);
            }
            Bf[i][s] = u.v;
        }
        U u; u.d[0] = u.d[1] = u.d[2] = u.d[3] = 0u;
        const int n = t4 * 64 + c * 16 + ln;
        if (g4 == 0) {                          // slots 64..71: x hi/lo pairs
            #pragma unroll
            for (int c4 = 0; c4 < 4; ++c4) {
                const unsigned int us = f2bf(fac * W_ih[n * 4 + c4]);
                u.d[c4] = us | (us << 16);
            }
        } else if (g4 == 1) {                   // slot 72: bias
            u.d[0] = f2bf(fac * (b_ih[n] + b_hh[n]));
        }
        Bf[i][2] = u.v;
    }

    // x FIFO: 32 duty lanes (8 batches x 4 comps), 4 per wave
    const bool xduty = ((tid & 15) == 0);
    int xbase = 0, xrowbyte = 0;
    float xw = 0.f, xn = 0.f;
    if (xduty) {
        const int v    = tid >> 4;              // 0..31
        const int bl   = v >> 2;                // local batch 0..7
        const int comp = v & 3;
        const int row  = ((bl & 6) << 1) | (bl & 1);   // perm(bl)
        xbase    = (b0 + bl) * (TSTEPS * 4) + comp;
        xrowbyte = (row * ROWB + 128 + 4 * comp) ^ ((row & 7) << 4);
        *(unsigned int*)(Abuf + xrowbyte) = split_pack(x[xbase]);   // seed x_0
        xw = x[xbase + 4 * 1];
        xn = x[xbase + 4 * 2];
    }
    // constant-1 bias column (slot 72, byte 144), both buffers, all rows
    if (tid < 32) {
        const int row = tid & 15, buf = tid >> 4;
        const int byte = (row * ROWB + 144) ^ ((row & 7) << 4);
        *(unsigned int*)(Abuf + buf * ABYTES + byte) = 0x3F80u;     // bf16(1.0)
    }
    __syncthreads();

    // Hoisted addresses
    int aoff[3];
    #pragma unroll
    for (int s = 0; s < 3; ++s)
        aoff[s] = (ln * ROWB + s * 64 + g4 * 16) ^ ((ln & 7) << 4);
    const int wrow  = g4 * 4 + p;               // this lane's C row (reg = p)
    const int woffp = (wrow * ROWB + 2 * (c * 16 + ln)) ^ ((wrow & 7) << 4);
    const int exw   = ((p * 4 + c) * 2) * 64 + l;          // write base (tile i += 64)
    const int exr   = (((1 - p) * 4 + c) * 2) * 64 + l;    // read base

    float cst = 0.f, hffin = 0.f;
    int cur = 0;

    // ---------------- recurrence ----------------
    for (int t = 0; t < TSTEPS; ++t) {
        float xn2 = 0.0f;
        if (xduty) {
            const int tt = (t + 3 < TSTEPS) ? t + 3 : TSTEPS - 1;
            xn2 = x[xbase + 4 * tt];
        }

        const unsigned char* Ab = Abuf + cur * ABYTES;
        const bf16x8 af0 = *(const bf16x8*)(Ab + aoff[0]);
        const bf16x8 af1 = *(const bf16x8*)(Ab + aoff[1]);
        const bf16x8 af2 = *(const bf16x8*)(Ab + aoff[2]);

        f32x4 accA = {0.f, 0.f, 0.f, 0.f}, accB = accA;
        accA = __builtin_amdgcn_mfma_f32_16x16x32_bf16(af0, Bf[0][0], accA, 0, 0, 0);
        accB = __builtin_amdgcn_mfma_f32_16x16x32_bf16(af0, Bf[1][0], accB, 0, 0, 0);
        accA = __builtin_amdgcn_mfma_f32_16x16x32_bf16(af1, Bf[0][1], accA, 0, 0, 0);
        accB = __builtin_amdgcn_mfma_f32_16x16x32_bf16(af1, Bf[1][1], accB, 0, 0, 0);
        accA = __builtin_amdgcn_mfma_f32_16x16x32_bf16(af2, Bf[0][2], accA, 0, 0, 0);
        accB = __builtin_amdgcn_mfma_f32_16x16x32_bf16(af2, Bf[1][2], accB, 0, 0, 0);

        // export the other wave-pair's r-row pre-activations
        ex[exw]      = accA[1 - p];
        ex[exw + 64] = accB[1 - p];
        __syncthreads();
        const float rA = ex[exr];
        const float rB = ex[exr + 64];

        // assemble this lane's 4 gates for batch row g4*4+p
        float aIv, aFv, aGv, aOv;
        if (p == 0) { aIv = accA[0]; aFv = accB[0]; aGv = rA;      aOv = rB;      }
        else        { aGv = accA[1]; aOv = accB[1]; aIv = rA;      aFv = rB;      }

        const float gi = rcp1p(__builtin_amdgcn_exp2f(aIv));
        const float gf = rcp1p(__builtin_amdgcn_exp2f(aFv));
        const float rg = rcp1p(__builtin_amdgcn_exp2f(aGv));
        const float gg = fmaf(-2.0f, rg, 1.0f);
        const float go = rcp1p(__builtin_amdgcn_exp2f(aOv));
        cst = fmaf(gf, cst, gi * gg);
        const float rc = rcp1p(__builtin_amdgcn_exp2f(cst * (2.0f * LOG2E)));
        const float th = fmaf(-2.0f, rc, 1.0f);
        const float hf = go * th;
        hffin = hf;

        unsigned char* An = Abuf + (cur ^ 1) * ABYTES;
        const unsigned int ub = f2bf(hf);
        const unsigned int up = __shfl_xor(ub, 1);
        if (!(ln & 1))
            *(unsigned int*)(An + woffp) = ub | (up << 16);
        if (xduty)
            *(unsigned int*)(An + xrowbyte) = split_pack(xw);
        xw = xn; xn = xn2;

        __syncthreads();
        cur ^= 1;
    }

    // ---------------- epilogue (exact fp32 two-stage) ----------------
    hf32[g4 * 2 + p][c * 16 + ln] = hffin;
    __syncthreads();

    for (int idx = tid; idx < BPB * 49; idx += 512) {
        const int bb = idx / 49, q = idx - bb * 49;
        float s = 0.0f;
        #pragma unroll 8
        for (int h = 0; h < 64; ++h) s += hf32[bb][h] * W_hr[q * 64 + h];
        hproj[bb][q] = s;
    }
    __syncthreads();
    for (int idx = tid; idx < BPB * 49; idx += 512) {
        const int bb = idx / 49, q2 = idx - bb * 49;
        float s = b_out[q2];
        #pragma unroll 7
        for (int q = 0; q < 49; ++q) s += hproj[bb][q] * W_out[q2 * 49 + q];
        out[(b0 + bb) * 49 + q2] = s;
    }
}

extern "C" void kernel_launch(void* const* d_in, const int* in_sizes, int n_in,
                              void* d_out, int out_size, void* d_ws, size_t ws_size,
                              hipStream_t stream) {
    (void)in_sizes; (void)n_in; (void)d_ws; (void)ws_size; (void)out_size;
    const float* x     = (const float*)d_in[0];
    const float* W_ih  = (const float*)d_in[1];
    const float* W_hh  = (const float*)d_in[2];
    const float* b_ih  = (const float*)d_in[3];
    const float* b_hh  = (const float*)d_in[4];
    const float* W_hr  = (const float*)d_in[5];
    const float* W_out = (const float*)d_in[6];
    const float* b_out = (const float*)d_in[7];
    float* outp = (float*)d_out;

    lstm_mfma8_kernel<<<dim3(2048 / BPB), dim3(512), 0, stream>>>(
        x, W_ih, W_hh, b_ih, b_hh, W_hr, W_out, b_out, outp);
}

// Round 11
// 310.097 us; speedup vs baseline: 1.0171x; 1.0171x over previous
//
#include <hip/hip_runtime.h>

#define TSTEPS 512
#define BPB    8                  // 8 batches/block: 2 chains x 4 (rows {0,4,8,12})
#define ROWB   256                // bytes per A row (96 k-slots used)
#define ABYTES (16 * ROWB)        // 4096
#define LOG2E  1.44269504088896340736f

typedef short bf16x8 __attribute__((ext_vector_type(8)));
typedef float f32x4  __attribute__((ext_vector_type(4)));

__device__ __forceinline__ unsigned int f2bf(float f) {   // RTN-even
    unsigned int u = __builtin_bit_cast(unsigned int, f);
    return (u + 0x7FFFu + ((u >> 16) & 1u)) >> 16;
}
__device__ __forceinline__ float bf2f(unsigned int us) {
    return __builtin_bit_cast(float, us << 16);
}
__device__ __forceinline__ unsigned int split_pack(float f) {  // hi | lo<<16
    unsigned int hi = f2bf(f);
    unsigned int lo = f2bf(f - bf2f(hi));
    return hi | (lo << 16);
}
__device__ __forceinline__ float rcp1p(float e) {   // 1/(1+e)
    return __builtin_amdgcn_rcpf(1.0f + e);
}

// R8 math + R10's log2e fold (both verified, absmax 9.77e-4):
//   gates i,f,o: B columns scaled by -log2e  -> sigmoid = rcp(1+exp2(acc))
//   gate  g:     B columns scaled by 2log2e  -> tanh    = fma(-2,rcp(1+exp2(acc)),1)
// NEW structure: grid 256 (1 block/CU), 4 waves; each wave interleaves TWO
// independent 4-batch chains (buffers [A0,A1,B0,B1]). Chain B's MFMA issue
// fills chain A's MFMA dep-chain latency; nonlinA's trans chain runs under
// chain B's matrix-pipe time (separate pipes). Deterministic in-wave overlap
// instead of round 8's phase-locked 2-blocks/CU. One barrier per step.
__global__ __launch_bounds__(256, 1) void lstm_mfma9_kernel(
    const float* __restrict__ x,      // [B, T, 4]
    const float* __restrict__ W_ih,   // [256, 4]
    const float* __restrict__ W_hh,   // [256, 49]
    const float* __restrict__ b_ih,   // [256]
    const float* __restrict__ b_hh,   // [256]
    const float* __restrict__ W_hr,   // [49, 64]
    const float* __restrict__ W_out,  // [49, 49]
    const float* __restrict__ b_out,  // [49]
    float* __restrict__ out)          // [B, 49]
{
    const int tid = threadIdx.x;
    const int w   = tid >> 6;         // wave 0..3 -> 16-col h-chunk
    const int l   = tid & 63;
    const int g4  = l >> 4;
    const int ln  = l & 15;
    const int b0  = blockIdx.x * BPB;

    // [A-cur, A-nxt, B-cur, B-nxt]
    __shared__ __align__(128) unsigned char Abuf[4 * ABYTES];
    __shared__ __align__(16)  float hf32[BPB][64];
    __shared__ float hproj[BPB][52];

    // ---------------- prologue ----------------
    for (int i = tid; i < (4 * ABYTES) / 4; i += 256)
        ((unsigned int*)Abuf)[i] = 0u;

    // M[k][n] = sum_q W_hr[q][k] * W_hh[n][q], this wave's 4 gate-cols
    float Msum[4][16];
    #pragma unroll
    for (int t4 = 0; t4 < 4; ++t4)
        #pragma unroll
        for (int i = 0; i < 16; ++i) Msum[t4][i] = 0.0f;

    for (int q = 0; q < 49; ++q) {
        float wr[16];
        #pragma unroll
        for (int s = 0; s < 2; ++s)
            #pragma unroll
            for (int j = 0; j < 8; ++j)
                wr[s * 8 + j] = W_hr[q * 64 + s * 32 + g4 * 8 + j];
        #pragma unroll
        for (int t4 = 0; t4 < 4; ++t4) {
            const float whh = W_hh[(t4 * 64 + w * 16 + ln) * 49 + q];
            #pragma unroll
            for (int i = 0; i < 16; ++i) Msum[t4][i] += whh * wr[i];
        }
    }

    // Resident B fragments with log2e factors folded in
    bf16x8 Bf[4][3];
    union U { unsigned int d[4]; bf16x8 v; };
    #pragma unroll
    for (int t4 = 0; t4 < 4; ++t4) {
        const float fac = (t4 == 2) ? 2.0f * LOG2E : -LOG2E;
        #pragma unroll
        for (int s = 0; s < 2; ++s) {
            U u;
            #pragma unroll
            for (int jj = 0; jj < 4; ++jj) {
                const unsigned int e0 = f2bf(fac * Msum[t4][s * 8 + 2 * jj]);
                const unsigned int e1 = f2bf(fac * Msum[t4][s * 8 + 2 * jj + 1]);
                u.d[jj] = e0 | (e1 << 16);
            }
            Bf[t4][s] = u.v;
        }
        U u; u.d[0] = u.d[1] = u.d[2] = u.d[3] = 0u;
        const int n = t4 * 64 + w * 16 + ln;
        if (g4 == 0) {                          // slots 64..71: x hi/lo pairs
            #pragma unroll
            for (int c4 = 0; c4 < 4; ++c4) {
                const unsigned int us = f2bf(fac * W_ih[n * 4 + c4]);
                u.d[c4] = us | (us << 16);
            }
        } else if (g4 == 1) {                   // slot 72: bias
            u.d[0] = f2bf(fac * (b_ih[n] + b_hh[n]));
        }
        Bf[t4][2] = u.v;
    }

    // x FIFO: 32 duty lanes (tid%8==0), v = tid>>3: bl = v>>2 (0..7), comp = v&3.
    // bl 0..3 -> chain A, 4..7 -> chain B; row = (bl&3)*4.
    const bool xduty = ((tid & 7) == 0);
    int xbase = 0, xrowbyte = 0;
    float xw = 0.f, xn = 0.f;
    if (xduty) {
        const int v     = tid >> 3;
        const int bl    = v >> 2;
        const int comp  = v & 3;
        const int chain = bl >> 2;
        const int row   = (bl & 3) * 4;
        xbase    = (b0 + bl) * (TSTEPS * 4) + comp;
        xrowbyte = chain * 2 * ABYTES +
                   ((row * ROWB + 128 + 4 * comp) ^ ((row & 7) << 4));
        *(unsigned int*)(Abuf + xrowbyte) = split_pack(x[xbase]);   // seed x_0
        xw = x[xbase + 4 * 1];
        xn = x[xbase + 4 * 2];
    }
    // constant-1 bias column (slot 72, byte 144) into all 4 buffers
    if (tid < 64) {
        const int row = tid & 15, buf = tid >> 4;
        const int byte = (row * ROWB + 144) ^ ((row & 7) << 4);
        *(unsigned int*)(Abuf + buf * ABYTES + byte) = 0x3F80u;     // bf16(1.0)
    }
    __syncthreads();

    // Hoisted addresses (identical pattern both chains)
    int aoff[3];
    #pragma unroll
    for (int s = 0; s < 3; ++s)
        aoff[s] = (ln * ROWB + s * 64 + g4 * 16) ^ ((ln & 7) << 4);
    const int wrow  = g4 * 4;                   // this lane's C row (r=0)
    const int woffp = (wrow * ROWB + 2 * (w * 16 + ln)) ^ ((wrow & 7) << 4);

    float cstA = 0.f, cstB = 0.f, hffinA = 0.f, hffinB = 0.f;
    int cur = 0;

    // ---------------- recurrence ----------------
    for (int t = 0; t < TSTEPS; ++t) {
        float xn2 = 0.0f;
        if (xduty) {
            const int tt = (t + 3 < TSTEPS) ? t + 3 : TSTEPS - 1;
            xn2 = x[xbase + 4 * tt];
        }

        const unsigned char* Aa = Abuf + cur * ABYTES;                // chain A
        const unsigned char* Ab = Abuf + 2 * ABYTES + cur * ABYTES;   // chain B
        const bf16x8 a0 = *(const bf16x8*)(Aa + aoff[0]);
        const bf16x8 a1 = *(const bf16x8*)(Aa + aoff[1]);
        const bf16x8 a2 = *(const bf16x8*)(Aa + aoff[2]);
        const bf16x8 b0f = *(const bf16x8*)(Ab + aoff[0]);
        const bf16x8 b1f = *(const bf16x8*)(Ab + aoff[1]);
        const bf16x8 b2f = *(const bf16x8*)(Ab + aoff[2]);

        f32x4 AI = {0.f,0.f,0.f,0.f}, AF = AI, AG = AI, AO = AI;
        f32x4 BI = AI, BF_ = AI, BG = AI, BO = AI;
        // chain A MFMAs
        AI = __builtin_amdgcn_mfma_f32_16x16x32_bf16(a0, Bf[0][0], AI, 0, 0, 0);
        AF = __builtin_amdgcn_mfma_f32_16x16x32_bf16(a0, Bf[1][0], AF, 0, 0, 0);
        AG = __builtin_amdgcn_mfma_f32_16x16x32_bf16(a0, Bf[2][0], AG, 0, 0, 0);
        AO = __builtin_amdgcn_mfma_f32_16x16x32_bf16(a0, Bf[3][0], AO, 0, 0, 0);
        AI = __builtin_amdgcn_mfma_f32_16x16x32_bf16(a1, Bf[0][1], AI, 0, 0, 0);
        AF = __builtin_amdgcn_mfma_f32_16x16x32_bf16(a1, Bf[1][1], AF, 0, 0, 0);
        AG = __builtin_amdgcn_mfma_f32_16x16x32_bf16(a1, Bf[2][1], AG, 0, 0, 0);
        AO = __builtin_amdgcn_mfma_f32_16x16x32_bf16(a1, Bf[3][1], AO, 0, 0, 0);
        AI = __builtin_amdgcn_mfma_f32_16x16x32_bf16(a2, Bf[0][2], AI, 0, 0, 0);
        AF = __builtin_amdgcn_mfma_f32_16x16x32_bf16(a2, Bf[1][2], AF, 0, 0, 0);
        AG = __builtin_amdgcn_mfma_f32_16x16x32_bf16(a2, Bf[2][2], AG, 0, 0, 0);
        AO = __builtin_amdgcn_mfma_f32_16x16x32_bf16(a2, Bf[3][2], AO, 0, 0, 0);
        // chain B MFMAs (independent -> issue while A's results are in flight)
        BI = __builtin_amdgcn_mfma_f32_16x16x32_bf16(b0f, Bf[0][0], BI, 0, 0, 0);
        BF_= __builtin_amdgcn_mfma_f32_16x16x32_bf16(b0f, Bf[1][0], BF_, 0, 0, 0);
        BG = __builtin_amdgcn_mfma_f32_16x16x32_bf16(b0f, Bf[2][0], BG, 0, 0, 0);
        BO = __builtin_amdgcn_mfma_f32_16x16x32_bf16(b0f, Bf[3][0], BO, 0, 0, 0);
        BI = __builtin_amdgcn_mfma_f32_16x16x32_bf16(b1f, Bf[0][1], BI, 0, 0, 0);
        BF_= __builtin_amdgcn_mfma_f32_16x16x32_bf16(b1f, Bf[1][1], BF_, 0, 0, 0);
        BG = __builtin_amdgcn_mfma_f32_16x16x32_bf16(b1f, Bf[2][1], BG, 0, 0, 0);
        BO = __builtin_amdgcn_mfma_f32_16x16x32_bf16(b1f, Bf[3][1], BO, 0, 0, 0);
        BI = __builtin_amdgcn_mfma_f32_16x16x32_bf16(b2f, Bf[0][2], BI, 0, 0, 0);
        BF_= __builtin_amdgcn_mfma_f32_16x16x32_bf16(b2f, Bf[1][2], BF_, 0, 0, 0);
        BG = __builtin_amdgcn_mfma_f32_16x16x32_bf16(b2f, Bf[2][2], BG, 0, 0, 0);
        BO = __builtin_amdgcn_mfma_f32_16x16x32_bf16(b2f, Bf[3][2], BO, 0, 0, 0);

        unsigned char* NA = Abuf + (cur ^ 1) * ABYTES;
        unsigned char* NB = Abuf + 2 * ABYTES + (cur ^ 1) * ABYTES;
        // nonlin A (VALU/trans) overlaps chain B's matrix-pipe occupancy
        {
            const float gi = rcp1p(__builtin_amdgcn_exp2f(AI[0]));
            const float gf = rcp1p(__builtin_amdgcn_exp2f(AF[0]));
            const float rg = rcp1p(__builtin_amdgcn_exp2f(AG[0]));
            const float gg = fmaf(-2.0f, rg, 1.0f);
            const float go = rcp1p(__builtin_amdgcn_exp2f(AO[0]));
            cstA = fmaf(gf, cstA, gi * gg);
            const float rc = rcp1p(__builtin_amdgcn_exp2f(cstA * (2.0f * LOG2E)));
            const float hf = go * fmaf(-2.0f, rc, 1.0f);
            hffinA = hf;
            const unsigned int ub = f2bf(hf);
            const unsigned int up = __shfl_xor(ub, 1);
            if (!(ln & 1))
                *(unsigned int*)(NA + woffp) = ub | (up << 16);
        }
        {
            const float gi = rcp1p(__builtin_amdgcn_exp2f(BI[0]));
            const float gf = rcp1p(__builtin_amdgcn_exp2f(BF_[0]));
            const float rg = rcp1p(__builtin_amdgcn_exp2f(BG[0]));
            const float gg = fmaf(-2.0f, rg, 1.0f);
            const float go = rcp1p(__builtin_amdgcn_exp2f(BO[0]));
            cstB = fmaf(gf, cstB, gi * gg);
            const float rc = rcp1p(__builtin_amdgcn_exp2f(cstB * (2.0f * LOG2E)));
            const float hf = go * fmaf(-2.0f, rc, 1.0f);
            hffinB = hf;
            const unsigned int ub = f2bf(hf);
            const unsigned int up = __shfl_xor(ub, 1);
            if (!(ln & 1))
                *(unsigned int*)(NB + woffp) = ub | (up << 16);
        }
        if (xduty)
            *(unsigned int*)(Abuf + (cur ^ 1) * ABYTES + xrowbyte) = split_pack(xw);
        xw = xn; xn = xn2;

        __syncthreads();
        cur ^= 1;
    }

    // ---------------- epilogue (exact fp32 two-stage) ----------------
    hf32[g4][w * 16 + ln]     = hffinA;   // chain A: local batch g4
    hf32[4 + g4][w * 16 + ln] = hffinB;   // chain B: local batch 4+g4
    __syncthreads();

    for (int idx = tid; idx < BPB * 49; idx += 256) {
        const int bb = idx / 49, q = idx - bb * 49;
        float s = 0.0f;
        #pragma unroll 8
        for (int h = 0; h < 64; ++h) s += hf32[bb][h] * W_hr[q * 64 + h];
        hproj[bb][q] = s;
    }
    __syncthreads();
    for (int idx = tid; idx < BPB * 49; idx += 256) {
        const int bb = idx / 49, q2 = idx - bb * 49;
        float s = b_out[q2];
        #pragma unroll 7
        for (int p = 0; p < 49; ++p) s += hproj[bb][p] * W_out[q2 * 49 + p];
        out[(b0 + bb) * 49 + q2] = s;
    }
}

extern "C" void kernel_launch(void* const* d_in, const int* in_sizes, int n_in,
                              void* d_out, int out_size, void* d_ws, size_t ws_size,
                              hipStream_t stream) {
    (void)in_sizes; (void)n_in; (void)d_ws; (void)ws_size; (void)out_size;
    const float* x     = (const float*)d_in[0];
    const float* W_ih  = (const float*)d_in[1];
    const float* W_hh  = (const float*)d_in[2];
    const float* b_ih  = (const float*)d_in[3];
    const float* b_hh  = (const float*)d_in[4];
    const float* W_hr  = (const float*)d_in[5];
    const float* W_out = (const float*)d_in[6];
    const float* b_out = (const float*)d_in[7];
    float* outp = (float*)d_out;

    lstm_mfma9_kernel<<<dim3(2048 / BPB), dim3(256), 0, stream>>>(
        x, W_ih, W_hh, b_ih, b_hh, W_hr, W_out, b_out, outp);
}

// Round 12
// 246.886 us; speedup vs baseline: 1.2775x; 1.2560x over previous
//
#include <hip/hip_runtime.h>

#define TSTEPS 512
#define BPB    4                  // batches per block, rows {0,4,8,12}
#define ROWB   256                // bytes per A row (96 k-slots used)
#define ABYTES (16 * ROWB)        // 4096
#define LOG2E  1.44269504088896340736f

typedef short bf16x8 __attribute__((ext_vector_type(8)));
typedef float f32x4  __attribute__((ext_vector_type(4)));

__device__ __forceinline__ unsigned int f2bf(float f) {   // RTN-even
    unsigned int u = __builtin_bit_cast(unsigned int, f);
    return (u + 0x7FFFu + ((u >> 16) & 1u)) >> 16;
}
__device__ __forceinline__ float bf2f(unsigned int us) {
    return __builtin_bit_cast(float, us << 16);
}
__device__ __forceinline__ unsigned int split_pack(float f) {  // hi | lo<<16
    unsigned int hi = f2bf(f);
    unsigned int lo = f2bf(f - bf2f(hi));
    return hi | (lo << 16);
}
__device__ __forceinline__ float rcp1p(float e) {   // 1/(1+e)
    return __builtin_amdgcn_rcpf(1.0f + e);
}

// Round-8 structure (best known: 224us) + two deltas:
//  1. PHASE STAGGER: each CU hosts 2 blocks; started symmetrically they lock
//     IN-PHASE (both MFMA together, then both VALU -> step = sum of pipes,
//     1144 cyc). Anti-phase is also an equilibrium and self-correcting under
//     matrix-pipe contention, and gives step = max(pipes) ~ 700. One block of
//     each pair sleeps ~576 cyc once before the t-loop to break the symmetry.
//  2. log2e folded into B (verified absmax-identical in R10/R11):
//     gates i,f,o scaled by -log2e -> sigmoid = rcp(1+exp2(acc));
//     gate g scaled by 2log2e     -> tanh    = fma(-2, rcp(1+exp2(acc)), 1).
// Everything else identical to round 8.
__global__ __launch_bounds__(256, 2) void lstm_mfma10_kernel(
    const float* __restrict__ x,      // [B, T, 4]
    const float* __restrict__ W_ih,   // [256, 4]
    const float* __restrict__ W_hh,   // [256, 49]
    const float* __restrict__ b_ih,   // [256]
    const float* __restrict__ b_hh,   // [256]
    const float* __restrict__ W_hr,   // [49, 64]
    const float* __restrict__ W_out,  // [49, 49]
    const float* __restrict__ b_out,  // [49]
    float* __restrict__ out)          // [B, 49]
{
    const int tid = threadIdx.x;
    const int w   = tid >> 6;
    const int l   = tid & 63;
    const int g4  = l >> 4;
    const int ln  = l & 15;
    const int b0  = blockIdx.x * BPB;

    __shared__ __align__(128) unsigned char Abuf[2 * ABYTES];
    __shared__ __align__(16)  float hf32[BPB][64];
    __shared__ float hproj[BPB][52];

    // ---------------- prologue ----------------
    for (int i = tid; i < (2 * ABYTES) / 4; i += 256)
        ((unsigned int*)Abuf)[i] = 0u;
    __syncthreads();

    // M[k][n] for this lane's 16 k-slots (k = s*32 + g4*8 + j, s=0,1) x 4 n-cols
    float Msum[4][16];
    #pragma unroll
    for (int t4 = 0; t4 < 4; ++t4)
        #pragma unroll
        for (int i = 0; i < 16; ++i) Msum[t4][i] = 0.0f;

    for (int p = 0; p < 49; ++p) {
        float wr[16];
        #pragma unroll
        for (int s = 0; s < 2; ++s)
            #pragma unroll
            for (int j = 0; j < 8; ++j)
                wr[s * 8 + j] = W_hr[p * 64 + s * 32 + g4 * 8 + j];
        #pragma unroll
        for (int t4 = 0; t4 < 4; ++t4) {
            const float whh = W_hh[(t4 * 64 + w * 16 + ln) * 49 + p];
            #pragma unroll
            for (int i = 0; i < 16; ++i) Msum[t4][i] += whh * wr[i];
        }
    }

    // Resident B fragments with log2e factors folded in
    bf16x8 Bf[4][3];
    union U { unsigned int d[4]; bf16x8 v; };
    #pragma unroll
    for (int t4 = 0; t4 < 4; ++t4) {
        const float fac = (t4 == 2) ? 2.0f * LOG2E : -LOG2E;
        #pragma unroll
        for (int s = 0; s < 2; ++s) {
            U u;
            #pragma unroll
            for (int jj = 0; jj < 4; ++jj) {
                const unsigned int e0 = f2bf(fac * Msum[t4][s * 8 + 2 * jj]);
                const unsigned int e1 = f2bf(fac * Msum[t4][s * 8 + 2 * jj + 1]);
                u.d[jj] = e0 | (e1 << 16);
            }
            Bf[t4][s] = u.v;
        }
        U u; u.d[0] = u.d[1] = u.d[2] = u.d[3] = 0u;
        const int n = t4 * 64 + w * 16 + ln;
        if (g4 == 0) {                          // slots 64..71: x hi/lo pairs
            #pragma unroll
            for (int c4 = 0; c4 < 4; ++c4) {
                const unsigned int us = f2bf(fac * W_ih[n * 4 + c4]);
                u.d[c4] = us | (us << 16);
            }
        } else if (g4 == 1) {                   // slot 72: bias
            u.d[0] = f2bf(fac * (b_ih[n] + b_hh[n]));
        }
        Bf[t4][2] = u.v;
    }

    // x FIFO: 16 duty lanes (4 batches x 4 comps), 4 per wave
    const bool xduty = ((tid & 15) == 0);
    int xbase = 0, xrowbyte = 0;
    float xw = 0.f, xn = 0.f;
    if (xduty) {
        const int v    = tid >> 4;          // 0..15
        const int bl   = v >> 2;            // local batch 0..3
        const int comp = v & 3;
        const int row  = bl * 4;            // rows {0,4,8,12}
        xbase    = (b0 + bl) * (TSTEPS * 4) + comp;
        xrowbyte = (row * ROWB + 128 + 4 * comp) ^ ((row & 7) << 4);
        *(unsigned int*)(Abuf + xrowbyte) = split_pack(x[xbase]);   // seed x_0
        xw = x[xbase + 4 * 1];
        xn = x[xbase + 4 * 2];
    }
    // constant-1 bias column (slot 72, byte 144) into both buffers, all rows
    if (tid < 32) {
        const int row = tid & 15, buf = tid >> 4;
        const int byte = (row * ROWB + 144) ^ ((row & 7) << 4);
        *(unsigned int*)(Abuf + buf * ABYTES + byte) = 0x3F80u;     // bf16(1.0)
    }
    __syncthreads();

    // ---- phase stagger: desynchronize the CU's two co-resident blocks ----
    // Parity differs under either pairing ((c, c+256) or (2c, 2c+1)).
    if ((blockIdx.x ^ (blockIdx.x >> 8)) & 1) {
        __builtin_amdgcn_s_sleep(8);    // ~512 cyc
        __builtin_amdgcn_s_sleep(1);    // ~64 cyc  -> ~half of the 1144-cyc step
    }

    // Hoisted addresses
    int aoff[3];
    #pragma unroll
    for (int s = 0; s < 3; ++s)
        aoff[s] = (ln * ROWB + s * 64 + g4 * 16) ^ ((ln & 7) << 4);
    const int wrow  = g4 * 4;               // this lane's valid C row (r=0)
    const int woffp = (wrow * ROWB + 2 * (w * 16 + ln)) ^ ((wrow & 7) << 4);

    float cst = 0.f;
    float hffin = 0.f;
    int cur = 0;

    // ---------------- recurrence ----------------
    for (int t = 0; t < TSTEPS; ++t) {
        float xn2 = 0.0f;
        if (xduty) {
            const int tt = (t + 3 < TSTEPS) ? t + 3 : TSTEPS - 1;
            xn2 = x[xbase + 4 * tt];
        }

        const unsigned char* Ab = Abuf + cur * ABYTES;
        const bf16x8 af0 = *(const bf16x8*)(Ab + aoff[0]);
        const bf16x8 af1 = *(const bf16x8*)(Ab + aoff[1]);
        const bf16x8 af2 = *(const bf16x8*)(Ab + aoff[2]);

        f32x4 aI = {0.f, 0.f, 0.f, 0.f}, aF = aI, aG = aI, aO = aI;
        aI = __builtin_amdgcn_mfma_f32_16x16x32_bf16(af0, Bf[0][0], aI, 0, 0, 0);
        aF = __builtin_amdgcn_mfma_f32_16x16x32_bf16(af0, Bf[1][0], aF, 0, 0, 0);
        aG = __builtin_amdgcn_mfma_f32_16x16x32_bf16(af0, Bf[2][0], aG, 0, 0, 0);
        aO = __builtin_amdgcn_mfma_f32_16x16x32_bf16(af0, Bf[3][0], aO, 0, 0, 0);
        aI = __builtin_amdgcn_mfma_f32_16x16x32_bf16(af1, Bf[0][1], aI, 0, 0, 0);
        aF = __builtin_amdgcn_mfma_f32_16x16x32_bf16(af1, Bf[1][1], aF, 0, 0, 0);
        aG = __builtin_amdgcn_mfma_f32_16x16x32_bf16(af1, Bf[2][1], aG, 0, 0, 0);
        aO = __builtin_amdgcn_mfma_f32_16x16x32_bf16(af1, Bf[3][1], aO, 0, 0, 0);
        aI = __builtin_amdgcn_mfma_f32_16x16x32_bf16(af2, Bf[0][2], aI, 0, 0, 0);
        aF = __builtin_amdgcn_mfma_f32_16x16x32_bf16(af2, Bf[1][2], aF, 0, 0, 0);
        aG = __builtin_amdgcn_mfma_f32_16x16x32_bf16(af2, Bf[2][2], aG, 0, 0, 0);
        aO = __builtin_amdgcn_mfma_f32_16x16x32_bf16(af2, Bf[3][2], aO, 0, 0, 0);

        unsigned char* An = Abuf + (cur ^ 1) * ABYTES;
        {
            const float gi = rcp1p(__builtin_amdgcn_exp2f(aI[0]));
            const float gf = rcp1p(__builtin_amdgcn_exp2f(aF[0]));
            const float rg = rcp1p(__builtin_amdgcn_exp2f(aG[0]));
            const float gg = fmaf(-2.0f, rg, 1.0f);
            const float go = rcp1p(__builtin_amdgcn_exp2f(aO[0]));
            cst = fmaf(gf, cst, gi * gg);
            const float rc = rcp1p(__builtin_amdgcn_exp2f(cst * (2.0f * LOG2E)));
            const float hf = go * fmaf(-2.0f, rc, 1.0f);
            hffin = hf;
            // pair-merge to b32: even lane packs (self | partner<<16)
            const unsigned int ub = f2bf(hf);
            const unsigned int up = __shfl_xor(ub, 1);
            if (!(ln & 1))
                *(unsigned int*)(An + woffp) = ub | (up << 16);
        }
        if (xduty)
            *(unsigned int*)(An + xrowbyte) = split_pack(xw);
        xw = xn; xn = xn2;

        __syncthreads();
        cur ^= 1;
    }

    // ---------------- epilogue (exact fp32 two-stage) ----------------
    hf32[g4][w * 16 + ln] = hffin;
    __syncthreads();

    for (int idx = tid; idx < BPB * 49; idx += 256) {
        const int bb = idx / 49, q = idx - bb * 49;
        float s = 0.0f;
        #pragma unroll 8
        for (int h = 0; h < 64; ++h) s += hf32[bb][h] * W_hr[q * 64 + h];
        hproj[bb][q] = s;
    }
    __syncthreads();
    for (int idx = tid; idx < BPB * 49; idx += 256) {
        const int bb = idx / 49, q2 = idx - bb * 49;
        float s = b_out[q2];
        #pragma unroll 7
        for (int p = 0; p < 49; ++p) s += hproj[bb][p] * W_out[q2 * 49 + p];
        out[(b0 + bb) * 49 + q2] = s;
    }
}

extern "C" void kernel_launch(void* const* d_in, const int* in_sizes, int n_in,
                              void* d_out, int out_size, void* d_ws, size_t ws_size,
                              hipStream_t stream) {
    (void)in_sizes; (void)n_in; (void)d_ws; (void)ws_size; (void)out_size;
    const float* x     = (const float*)d_in[0];
    const float* W_ih  = (const float*)d_in[1];
    const float* W_hh  = (const float*)d_in[2];
    const float* b_ih  = (const float*)d_in[3];
    const float* b_hh  = (const float*)d_in[4];
    const float* W_hr  = (const float*)d_in[5];
    const float* W_out = (const float*)d_in[6];
    const float* b_out = (const float*)d_in[7];
    float* outp = (float*)d_out;

    lstm_mfma10_kernel<<<dim3(2048 / BPB), dim3(256), 0, stream>>>(
        x, W_ih, W_hh, b_ih, b_hh, W_hr, W_out, b_out, outp);
}

// Round 13
// 239.082 us; speedup vs baseline: 1.3192x; 1.0326x over previous
//
#include <hip/hip_runtime.h>

#define TSTEPS 512
#define BPB    4                  // batches per block, rows {0,4,8,12}
#define ROWB   256                // bytes per A row (96 k-slots used)
#define ABYTES (16 * ROWB)        // 4096
#define LOG2E  1.44269504088896340736f

typedef short bf16x8 __attribute__((ext_vector_type(8)));
typedef float f32x4  __attribute__((ext_vector_type(4)));

__device__ __forceinline__ unsigned int f2bf(float f) {   // RTN-even
    unsigned int u = __builtin_bit_cast(unsigned int, f);
    return (u + 0x7FFFu + ((u >> 16) & 1u)) >> 16;
}
__device__ __forceinline__ float bf2f(unsigned int us) {
    return __builtin_bit_cast(float, us << 16);
}
__device__ __forceinline__ unsigned int split_pack(float f) {  // hi | lo<<16
    unsigned int hi = f2bf(f);
    unsigned int lo = f2bf(f - bf2f(hi));
    return hi | (lo << 16);
}
__device__ __forceinline__ float rcp1p(float e) {   // 1/(1+e)
    return __builtin_amdgcn_rcpf(1.0f + e);
}

// Round-8 structure (best known: 224us) consolidated:
//  * NO stagger (R12 isolated it as a regression).
//  * log2e folded into B (absmax-identical across R10-R12):
//    gates i,f,o scaled by -log2e -> sigmoid = rcp(1+exp2(acc));
//    gate g scaled by 2log2e     -> tanh    = fma(-2, rcp(1+exp2(acc)), 1).
//  * hf stored as plain b16 (no shfl pair-merge: conflict counter proved
//    identical either way; the merge only added a DS-permute to the chain).
//  * MFMA accumulation split: s=0,1 chained + s=2 in a separate acc, summed
//    at the end -> shorter serial MFMA dependency.
__global__ __launch_bounds__(256, 2) void lstm_mfma11_kernel(
    const float* __restrict__ x,      // [B, T, 4]
    const float* __restrict__ W_ih,   // [256, 4]
    const float* __restrict__ W_hh,   // [256, 49]
    const float* __restrict__ b_ih,   // [256]
    const float* __restrict__ b_hh,   // [256]
    const float* __restrict__ W_hr,   // [49, 64]
    const float* __restrict__ W_out,  // [49, 49]
    const float* __restrict__ b_out,  // [49]
    float* __restrict__ out)          // [B, 49]
{
    const int tid = threadIdx.x;
    const int w   = tid >> 6;
    const int l   = tid & 63;
    const int g4  = l >> 4;
    const int ln  = l & 15;
    const int b0  = blockIdx.x * BPB;

    __shared__ __align__(128) unsigned char Abuf[2 * ABYTES];
    __shared__ __align__(16)  float hf32[BPB][64];
    __shared__ float hproj[BPB][52];

    // ---------------- prologue ----------------
    for (int i = tid; i < (2 * ABYTES) / 4; i += 256)
        ((unsigned int*)Abuf)[i] = 0u;
    __syncthreads();

    // M[k][n] for this lane's 16 k-slots (k = s*32 + g4*8 + j, s=0,1) x 4 n-cols
    float Msum[4][16];
    #pragma unroll
    for (int t4 = 0; t4 < 4; ++t4)
        #pragma unroll
        for (int i = 0; i < 16; ++i) Msum[t4][i] = 0.0f;

    for (int p = 0; p < 49; ++p) {
        float wr[16];
        #pragma unroll
        for (int s = 0; s < 2; ++s)
            #pragma unroll
            for (int j = 0; j < 8; ++j)
                wr[s * 8 + j] = W_hr[p * 64 + s * 32 + g4 * 8 + j];
        #pragma unroll
        for (int t4 = 0; t4 < 4; ++t4) {
            const float whh = W_hh[(t4 * 64 + w * 16 + ln) * 49 + p];
            #pragma unroll
            for (int i = 0; i < 16; ++i) Msum[t4][i] += whh * wr[i];
        }
    }

    // Resident B fragments with log2e factors folded in
    bf16x8 Bf[4][3];
    union U { unsigned int d[4]; bf16x8 v; };
    #pragma unroll
    for (int t4 = 0; t4 < 4; ++t4) {
        const float fac = (t4 == 2) ? 2.0f * LOG2E : -LOG2E;
        #pragma unroll
        for (int s = 0; s < 2; ++s) {
            U u;
            #pragma unroll
            for (int jj = 0; jj < 4; ++jj) {
                const unsigned int e0 = f2bf(fac * Msum[t4][s * 8 + 2 * jj]);
                const unsigned int e1 = f2bf(fac * Msum[t4][s * 8 + 2 * jj + 1]);
                u.d[jj] = e0 | (e1 << 16);
            }
            Bf[t4][s] = u.v;
        }
        U u; u.d[0] = u.d[1] = u.d[2] = u.d[3] = 0u;
        const int n = t4 * 64 + w * 16 + ln;
        if (g4 == 0) {                          // slots 64..71: x hi/lo pairs
            #pragma unroll
            for (int c4 = 0; c4 < 4; ++c4) {
                const unsigned int us = f2bf(fac * W_ih[n * 4 + c4]);
                u.d[c4] = us | (us << 16);
            }
        } else if (g4 == 1) {                   // slot 72: bias
            u.d[0] = f2bf(fac * (b_ih[n] + b_hh[n]));
        }
        Bf[t4][2] = u.v;
    }

    // x FIFO: 16 duty lanes (4 batches x 4 comps), 4 per wave
    const bool xduty = ((tid & 15) == 0);
    int xbase = 0, xrowbyte = 0;
    float xw = 0.f, xn = 0.f;
    if (xduty) {
        const int v    = tid >> 4;          // 0..15
        const int bl   = v >> 2;            // local batch 0..3
        const int comp = v & 3;
        const int row  = bl * 4;            // rows {0,4,8,12}
        xbase    = (b0 + bl) * (TSTEPS * 4) + comp;
        xrowbyte = (row * ROWB + 128 + 4 * comp) ^ ((row & 7) << 4);
        *(unsigned int*)(Abuf + xrowbyte) = split_pack(x[xbase]);   // seed x_0
        xw = x[xbase + 4 * 1];
        xn = x[xbase + 4 * 2];
    }
    // constant-1 bias column (slot 72, byte 144) into both buffers, all rows
    if (tid < 32) {
        const int row = tid & 15, buf = tid >> 4;
        const int byte = (row * ROWB + 144) ^ ((row & 7) << 4);
        *(unsigned int*)(Abuf + buf * ABYTES + byte) = 0x3F80u;     // bf16(1.0)
    }
    __syncthreads();

    // Hoisted addresses
    int aoff[3];
    #pragma unroll
    for (int s = 0; s < 3; ++s)
        aoff[s] = (ln * ROWB + s * 64 + g4 * 16) ^ ((ln & 7) << 4);
    const int wrow  = g4 * 4;               // this lane's valid C row (r=0)
    const int woffp = (wrow * ROWB + 2 * (w * 16 + ln)) ^ ((wrow & 7) << 4);

    float cst = 0.f;
    float hffin = 0.f;
    int cur = 0;

    // ---------------- recurrence ----------------
    for (int t = 0; t < TSTEPS; ++t) {
        float xn2 = 0.0f;
        if (xduty) {
            const int tt = (t + 3 < TSTEPS) ? t + 3 : TSTEPS - 1;
            xn2 = x[xbase + 4 * tt];
        }

        const unsigned char* Ab = Abuf + cur * ABYTES;
        const bf16x8 af0 = *(const bf16x8*)(Ab + aoff[0]);
        const bf16x8 af1 = *(const bf16x8*)(Ab + aoff[1]);
        const bf16x8 af2 = *(const bf16x8*)(Ab + aoff[2]);

        // split accumulation: (s0 -> s1 chained) + (s2 separate), sum at end
        f32x4 aI = {0.f, 0.f, 0.f, 0.f}, aF = aI, aG = aI, aO = aI;
        f32x4 bI = aI, bF = aI, bG = aI, bO = aI;
        aI = __builtin_amdgcn_mfma_f32_16x16x32_bf16(af0, Bf[0][0], aI, 0, 0, 0);
        aF = __builtin_amdgcn_mfma_f32_16x16x32_bf16(af0, Bf[1][0], aF, 0, 0, 0);
        aG = __builtin_amdgcn_mfma_f32_16x16x32_bf16(af0, Bf[2][0], aG, 0, 0, 0);
        aO = __builtin_amdgcn_mfma_f32_16x16x32_bf16(af0, Bf[3][0], aO, 0, 0, 0);
        bI = __builtin_amdgcn_mfma_f32_16x16x32_bf16(af2, Bf[0][2], bI, 0, 0, 0);
        bF = __builtin_amdgcn_mfma_f32_16x16x32_bf16(af2, Bf[1][2], bF, 0, 0, 0);
        bG = __builtin_amdgcn_mfma_f32_16x16x32_bf16(af2, Bf[2][2], bG, 0, 0, 0);
        bO = __builtin_amdgcn_mfma_f32_16x16x32_bf16(af2, Bf[3][2], bO, 0, 0, 0);
        aI = __builtin_amdgcn_mfma_f32_16x16x32_bf16(af1, Bf[0][1], aI, 0, 0, 0);
        aF = __builtin_amdgcn_mfma_f32_16x16x32_bf16(af1, Bf[1][1], aF, 0, 0, 0);
        aG = __builtin_amdgcn_mfma_f32_16x16x32_bf16(af1, Bf[2][1], aG, 0, 0, 0);
        aO = __builtin_amdgcn_mfma_f32_16x16x32_bf16(af1, Bf[3][1], aO, 0, 0, 0);

        unsigned char* An = Abuf + (cur ^ 1) * ABYTES;
        {
            const float gi = rcp1p(__builtin_amdgcn_exp2f(aI[0] + bI[0]));
            const float gf = rcp1p(__builtin_amdgcn_exp2f(aF[0] + bF[0]));
            const float rg = rcp1p(__builtin_amdgcn_exp2f(aG[0] + bG[0]));
            const float gg = fmaf(-2.0f, rg, 1.0f);
            const float go = rcp1p(__builtin_amdgcn_exp2f(aO[0] + bO[0]));
            cst = fmaf(gf, cst, gi * gg);
            const float rc = rcp1p(__builtin_amdgcn_exp2f(cst * (2.0f * LOG2E)));
            const float hf = go * fmaf(-2.0f, rc, 1.0f);
            hffin = hf;
            *(unsigned short*)(An + woffp) = (unsigned short)f2bf(hf);
        }
        if (xduty)
            *(unsigned int*)(An + xrowbyte) = split_pack(xw);
        xw = xn; xn = xn2;

        __syncthreads();
        cur ^= 1;
    }

    // ---------------- epilogue (exact fp32 two-stage) ----------------
    hf32[g4][w * 16 + ln] = hffin;
    __syncthreads();

    for (int idx = tid; idx < BPB * 49; idx += 256) {
        const int bb = idx / 49, q = idx - bb * 49;
        float s = 0.0f;
        #pragma unroll 8
        for (int h = 0; h < 64; ++h) s += hf32[bb][h] * W_hr[q * 64 + h];
        hproj[bb][q] = s;
    }
    __syncthreads();
    for (int idx = tid; idx < BPB * 49; idx += 256) {
        const int bb = idx / 49, q2 = idx - bb * 49;
        float s = b_out[q2];
        #pragma unroll 7
        for (int p = 0; p < 49; ++p) s += hproj[bb][p] * W_out[q2 * 49 + p];
        out[(b0 + bb) * 49 + q2] = s;
    }
}

extern "C" void kernel_launch(void* const* d_in, const int* in_sizes, int n_in,
                              void* d_out, int out_size, void* d_ws, size_t ws_size,
                              hipStream_t stream) {
    (void)in_sizes; (void)n_in; (void)d_ws; (void)ws_size; (void)out_size;
    const float* x     = (const float*)d_in[0];
    const float* W_ih  = (const float*)d_in[1];
    const float* W_hh  = (const float*)d_in[2];
    const float* b_ih  = (const float*)d_in[3];
    const float* b_hh  = (const float*)d_in[4];
    const float* W_hr  = (const float*)d_in[5];
    const float* W_out = (const float*)d_in[6];
    const float* b_out = (const float*)d_in[7];
    float* outp = (float*)d_out;

    lstm_mfma11_kernel<<<dim3(2048 / BPB), dim3(256), 0, stream>>>(
        x, W_ih, W_hh, b_ih, b_hh, W_hr, W_out, b_out, outp);
}

// Round 14
// 201.066 us; speedup vs baseline: 1.5686x; 1.1891x over previous
//
#include <hip/hip_runtime.h>

#define TSTEPS 512
#define BPB    4                  // batches per block, A rows {0,4,8,12}
#define AROWB  128                // Abuf row bytes (hf slots 0..63 only)
#define ABYTES (16 * AROWB)       // 2048
#define LOG2E  1.44269504088896340736f

typedef short bf16x8 __attribute__((ext_vector_type(8)));
typedef float f32x4  __attribute__((ext_vector_type(4)));

__device__ __forceinline__ unsigned int f2bf(float f) {   // RTN-even
    unsigned int u = __builtin_bit_cast(unsigned int, f);
    return (u + 0x7FFFu + ((u >> 16) & 1u)) >> 16;
}
__device__ __forceinline__ float bf2f(unsigned int us) {
    return __builtin_bit_cast(float, us << 16);
}
__device__ __forceinline__ unsigned int split_pack(float f) {  // hi | lo<<16
    unsigned int hi = f2bf(f);
    unsigned int lo = f2bf(f - bf2f(hi));
    return hi | (lo << 16);
}
__device__ __forceinline__ float rcp1p(float e) {   // 1/(1+e)
    return __builtin_amdgcn_rcpf(1.0f + e);
}

// R8 skeleton (best known) with issued-work cuts:
//  * Abuf carries ONLY hf (K-steps 0,1): 16 rows x 128B, double-buffered.
//    Swizzle ^((r&7)<<4)^((r&8)<<2): b128 reads conflict-free (lanes 0-7 and
//    8-15 each cover all 8 bank-octets); b16 writes to rows {0,4,8,12} land
//    on octets {0,16,8,24} -> kills the 12.6M/dispatch write conflicts of the
//    old ((r&7)<<4)-only swizzle (rows 0,8 collided).
//  * x + bias (K-step 2) live in a STATIC Xbuf[16 steps][16 rows][64B]:
//    bias/zero rows written once; x written once per 16 steps from a
//    1-value/thread prefetch register (loaded a full chunk ahead). Removes
//    the per-step masked global load + split_pack + conditional ds_write.
//  * log2e folded into B (absmax-identical R10-R13): sigmoid = rcp1p(exp2),
//    tanh = fma(-2, rcp1p(exp2), 1).
//  * hf store via v_cvt_pk_bf16_f32 (1 op, RTN-even == f2bf bit-exact).
__global__ __launch_bounds__(256, 2) void lstm_mfma12_kernel(
    const float* __restrict__ x,      // [B, T, 4]
    const float* __restrict__ W_ih,   // [256, 4]
    const float* __restrict__ W_hh,   // [256, 49]
    const float* __restrict__ b_ih,   // [256]
    const float* __restrict__ b_hh,   // [256]
    const float* __restrict__ W_hr,   // [49, 64]
    const float* __restrict__ W_out,  // [49, 49]
    const float* __restrict__ b_out,  // [49]
    float* __restrict__ out)          // [B, 49]
{
    const int tid = threadIdx.x;
    const int w   = tid >> 6;
    const int l   = tid & 63;
    const int g4  = l >> 4;
    const int ln  = l & 15;
    const int b0  = blockIdx.x * BPB;

    __shared__ __align__(128) unsigned char Abuf[2 * ABYTES];      // 4KB hf dbuf
    __shared__ __align__(128) unsigned char Xbuf[16 * 16 * 64];    // 16KB x/bias
    __shared__ __align__(16)  float hf32[BPB][64];
    __shared__ float hproj[BPB][52];

    // ---------------- prologue ----------------
    for (int i = tid; i < (2 * ABYTES) / 4; i += 256)
        ((unsigned int*)Abuf)[i] = 0u;
    for (int i = tid; i < (16 * 16 * 64) / 4; i += 256)
        ((unsigned int*)Xbuf)[i] = 0u;
    __syncthreads();   // zero-init complete before targeted writes below

    // M[k][n] for this lane's 16 k-slots (k = s*32 + g4*8 + j, s=0,1) x 4 n-cols
    float Msum[4][16];
    #pragma unroll
    for (int t4 = 0; t4 < 4; ++t4)
        #pragma unroll
        for (int i = 0; i < 16; ++i) Msum[t4][i] = 0.0f;

    for (int p = 0; p < 49; ++p) {
        float wr[16];
        #pragma unroll
        for (int s = 0; s < 2; ++s)
            #pragma unroll
            for (int j = 0; j < 8; ++j)
                wr[s * 8 + j] = W_hr[p * 64 + s * 32 + g4 * 8 + j];
        #pragma unroll
        for (int t4 = 0; t4 < 4; ++t4) {
            const float whh = W_hh[(t4 * 64 + w * 16 + ln) * 49 + p];
            #pragma unroll
            for (int i = 0; i < 16; ++i) Msum[t4][i] += whh * wr[i];
        }
    }

    // Resident B fragments with log2e factors folded in
    bf16x8 Bf[4][3];
    union U { unsigned int d[4]; bf16x8 v; };
    #pragma unroll
    for (int t4 = 0; t4 < 4; ++t4) {
        const float fac = (t4 == 2) ? 2.0f * LOG2E : -LOG2E;
        #pragma unroll
        for (int s = 0; s < 2; ++s) {
            U u;
            #pragma unroll
            for (int jj = 0; jj < 4; ++jj) {
                const unsigned int e0 = f2bf(fac * Msum[t4][s * 8 + 2 * jj]);
                const unsigned int e1 = f2bf(fac * Msum[t4][s * 8 + 2 * jj + 1]);
                u.d[jj] = e0 | (e1 << 16);
            }
            Bf[t4][s] = u.v;
        }
        U u; u.d[0] = u.d[1] = u.d[2] = u.d[3] = 0u;
        const int n = t4 * 64 + w * 16 + ln;
        if (g4 == 0) {                          // slots 64..71: x hi/lo pairs
            #pragma unroll
            for (int c4 = 0; c4 < 4; ++c4) {
                const unsigned int us = f2bf(fac * W_ih[n * 4 + c4]);
                u.d[c4] = us | (us << 16);
            }
        } else if (g4 == 1) {                   // slot 72: bias
            u.d[0] = f2bf(fac * (b_ih[n] + b_hh[n]));
        }
        Bf[t4][2] = u.v;
    }

    // Xbuf static part: constant-1 bias column (slot 72 -> row byte 16),
    // every step-slot tt, every row. One write per thread.
    {
        const int tt0 = tid >> 4, row = tid & 15;
        const int byte = tt0 * 1024 + (((row * 64) + 16) ^ ((row & 7) << 4));
        *(unsigned int*)(Xbuf + byte) = 0x3F80u;        // bf16(1.0), lo = 0
    }

    // x chunk ownership: thread -> (batch bl, step-in-chunk xtt, comp)
    const int xbl = tid >> 6, xtt = (tid >> 2) & 15, xcomp = tid & 3;
    const int xrow = xbl * 4;
    const int xwb  = xtt * 1024 +
                     (((xrow * 64) + (xcomp * 4)) ^ ((xrow & 7) << 4));
    const long xgbase = ((long)(b0 + xbl) * TSTEPS) * 4 + xcomp;
    float xreg = x[xgbase + xtt * 4];                    // chunk 0 value
    __syncthreads();

    // Hoisted addresses (Abuf swizzle: ^((r&7)<<4) ^ ((r&8)<<2))
    const int axor = ((ln & 7) << 4) ^ ((ln & 8) << 2);
    const int aoff0 = ((ln * AROWB) + (g4 * 16)) ^ axor;
    const int aoff1 = ((ln * AROWB) + 64 + (g4 * 16)) ^ axor;
    const int xroff = ((ln * 64) + (g4 * 16)) ^ ((ln & 7) << 4);
    const int wrow  = g4 * 4;                // this lane's valid C row (r=0)
    const int woffp = ((wrow * AROWB) + 2 * (w * 16 + ln)) ^
                      (((wrow & 7) << 4) ^ ((wrow & 8) << 2));

    float cst = 0.f;
    float hffin = 0.f;
    int cur = 0;
    int xrcur = xroff;

    // ---------------- recurrence ----------------
    for (int t = 0; t < TSTEPS; ++t) {
        if ((t & 15) == 0) {
            // publish this chunk's x (prefetched 16 steps ago), then prefetch next
            *(unsigned int*)(Xbuf + xwb) = split_pack(xreg);
            __syncthreads();
            const int nc = ((t >> 4) + 1 < 32) ? (t >> 4) + 1 : 31;
            xreg = x[xgbase + (nc * 16 + xtt) * 4];
            xrcur = xroff;
        }

        const unsigned char* Ab = Abuf + cur * ABYTES;
        const bf16x8 af0 = *(const bf16x8*)(Ab + aoff0);
        const bf16x8 af1 = *(const bf16x8*)(Ab + aoff1);
        const bf16x8 af2 = *(const bf16x8*)(Xbuf + xrcur);
        xrcur += 1024;

        f32x4 aI = {0.f, 0.f, 0.f, 0.f}, aF = aI, aG = aI, aO = aI;
        aI = __builtin_amdgcn_mfma_f32_16x16x32_bf16(af0, Bf[0][0], aI, 0, 0, 0);
        aF = __builtin_amdgcn_mfma_f32_16x16x32_bf16(af0, Bf[1][0], aF, 0, 0, 0);
        aG = __builtin_amdgcn_mfma_f32_16x16x32_bf16(af0, Bf[2][0], aG, 0, 0, 0);
        aO = __builtin_amdgcn_mfma_f32_16x16x32_bf16(af0, Bf[3][0], aO, 0, 0, 0);
        aI = __builtin_amdgcn_mfma_f32_16x16x32_bf16(af1, Bf[0][1], aI, 0, 0, 0);
        aF = __builtin_amdgcn_mfma_f32_16x16x32_bf16(af1, Bf[1][1], aF, 0, 0, 0);
        aG = __builtin_amdgcn_mfma_f32_16x16x32_bf16(af1, Bf[2][1], aG, 0, 0, 0);
        aO = __builtin_amdgcn_mfma_f32_16x16x32_bf16(af1, Bf[3][1], aO, 0, 0, 0);
        aI = __builtin_amdgcn_mfma_f32_16x16x32_bf16(af2, Bf[0][2], aI, 0, 0, 0);
        aF = __builtin_amdgcn_mfma_f32_16x16x32_bf16(af2, Bf[1][2], aF, 0, 0, 0);
        aG = __builtin_amdgcn_mfma_f32_16x16x32_bf16(af2, Bf[2][2], aG, 0, 0, 0);
        aO = __builtin_amdgcn_mfma_f32_16x16x32_bf16(af2, Bf[3][2], aO, 0, 0, 0);

        unsigned char* An = Abuf + (cur ^ 1) * ABYTES;
        {
            const float gi = rcp1p(__builtin_amdgcn_exp2f(aI[0]));
            const float gf = rcp1p(__builtin_amdgcn_exp2f(aF[0]));
            const float rg = rcp1p(__builtin_amdgcn_exp2f(aG[0]));
            const float gg = fmaf(-2.0f, rg, 1.0f);
            const float go = rcp1p(__builtin_amdgcn_exp2f(aO[0]));
            cst = fmaf(gf, cst, gi * gg);
            const float rc = rcp1p(__builtin_amdgcn_exp2f(cst * (2.0f * LOG2E)));
            const float hf = go * fmaf(-2.0f, rc, 1.0f);
            hffin = hf;
            unsigned int pk;
            asm("v_cvt_pk_bf16_f32 %0, %1, %2" : "=v"(pk) : "v"(hf), "v"(0.0f));
            *(unsigned short*)(An + woffp) = (unsigned short)pk;
        }

        __syncthreads();
        cur ^= 1;
    }

    // ---------------- epilogue (exact fp32 two-stage) ----------------
    hf32[g4][w * 16 + ln] = hffin;
    __syncthreads();

    for (int idx = tid; idx < BPB * 49; idx += 256) {
        const int bb = idx / 49, q = idx - bb * 49;
        float s = 0.0f;
        #pragma unroll 8
        for (int h = 0; h < 64; ++h) s += hf32[bb][h] * W_hr[q * 64 + h];
        hproj[bb][q] = s;
    }
    __syncthreads();
    for (int idx = tid; idx < BPB * 49; idx += 256) {
        const int bb = idx / 49, q2 = idx - bb * 49;
        float s = b_out[q2];
        #pragma unroll 7
        for (int p = 0; p < 49; ++p) s += hproj[bb][p] * W_out[q2 * 49 + p];
        out[(b0 + bb) * 49 + q2] = s;
    }
}

extern "C" void kernel_launch(void* const* d_in, const int* in_sizes, int n_in,
                              void* d_out, int out_size, void* d_ws, size_t ws_size,
                              hipStream_t stream) {
    (void)in_sizes; (void)n_in; (void)d_ws; (void)ws_size; (void)out_size;
    const float* x     = (const float*)d_in[0];
    const float* W_ih  = (const float*)d_in[1];
    const float* W_hh  = (const float*)d_in[2];
    const float* b_ih  = (const float*)d_in[3];
    const float* b_hh  = (const float*)d_in[4];
    const float* W_hr  = (const float*)d_in[5];
    const float* W_out = (const float*)d_in[6];
    const float* b_out = (const float*)d_in[7];
    float* outp = (float*)d_out;

    lstm_mfma12_kernel<<<dim3(2048 / BPB), dim3(256), 0, stream>>>(
        x, W_ih, W_hh, b_ih, b_hh, W_hr, W_out, b_out, outp);
}

// Round 15
// 189.371 us; speedup vs baseline: 1.6655x; 1.0618x over previous
//
#include <hip/hip_runtime.h>

#define TSTEPS 512
#define BPB    4                  // batches per block, A rows {0,4,8,12}
#define AROWB  128                // Abuf row bytes (hf slots 0..63 only)
#define ABYTES (16 * AROWB)       // 2048
#define XSLOTB 1040               // Xbuf per-step-slot stride: 1024+16 ->
                                  // bank shift 4/slot -> refill writes conflict-free
#define LOG2E  1.44269504088896340736f

typedef short bf16x8 __attribute__((ext_vector_type(8)));
typedef float f32x4  __attribute__((ext_vector_type(4)));

__device__ __forceinline__ unsigned int f2bf(float f) {   // RTN-even
    unsigned int u = __builtin_bit_cast(unsigned int, f);
    return (u + 0x7FFFu + ((u >> 16) & 1u)) >> 16;
}
__device__ __forceinline__ float bf2f(unsigned int us) {
    return __builtin_bit_cast(float, us << 16);
}
__device__ __forceinline__ unsigned int split_pack(float f) {  // hi | lo<<16
    unsigned int hi = f2bf(f);
    unsigned int lo = f2bf(f - bf2f(hi));
    return hi | (lo << 16);
}
__device__ __forceinline__ float rcp1p(float e) {   // 1/(1+e)
    return __builtin_amdgcn_rcpf(1.0f + e);
}

// R14 (201us) + issue mop-up:
//  * Xbuf slot stride 1040 (was 1024): chunk-refill writes previously put all
//    64 lanes of a wave on 4 banks (slot stride = 0 mod 32 banks -> 16-way);
//    stride 260 dwords = +4 banks/slot spreads them 2-lanes/bank (free).
//  * Hoisted ZV zero accumulator: first MFMA of each gate takes loop-invariant
//    ZV as C-in -> compiler need not re-materialize 16 zero movs per step.
//  * LDS double-buffer via XOR-toggle of hoisted byte offsets (aoff0/1, woffp
//    ^= ABYTES) instead of per-step pointer arithmetic.
// Math identical to R8/R14 (absmax 9.77e-4 expected bit-identical).
__global__ __launch_bounds__(256, 2) void lstm_mfma13_kernel(
    const float* __restrict__ x,      // [B, T, 4]
    const float* __restrict__ W_ih,   // [256, 4]
    const float* __restrict__ W_hh,   // [256, 49]
    const float* __restrict__ b_ih,   // [256]
    const float* __restrict__ b_hh,   // [256]
    const float* __restrict__ W_hr,   // [49, 64]
    const float* __restrict__ W_out,  // [49, 49]
    const float* __restrict__ b_out,  // [49]
    float* __restrict__ out)          // [B, 49]
{
    const int tid = threadIdx.x;
    const int w   = tid >> 6;
    const int l   = tid & 63;
    const int g4  = l >> 4;
    const int ln  = l & 15;
    const int b0  = blockIdx.x * BPB;

    __shared__ __align__(128) unsigned char Abuf[2 * ABYTES];      // 4KB hf dbuf
    __shared__ __align__(128) unsigned char Xbuf[16 * XSLOTB];     // ~16.3KB x/bias
    __shared__ __align__(16)  float hf32[BPB][64];
    __shared__ float hproj[BPB][52];

    // ---------------- prologue ----------------
    for (int i = tid; i < (2 * ABYTES) / 4; i += 256)
        ((unsigned int*)Abuf)[i] = 0u;
    for (int i = tid; i < (16 * XSLOTB) / 4; i += 256)
        ((unsigned int*)Xbuf)[i] = 0u;
    __syncthreads();   // zero-init complete before targeted writes below

    // M[k][n] for this lane's 16 k-slots (k = s*32 + g4*8 + j, s=0,1) x 4 n-cols
    float Msum[4][16];
    #pragma unroll
    for (int t4 = 0; t4 < 4; ++t4)
        #pragma unroll
        for (int i = 0; i < 16; ++i) Msum[t4][i] = 0.0f;

    for (int p = 0; p < 49; ++p) {
        float wr[16];
        #pragma unroll
        for (int s = 0; s < 2; ++s)
            #pragma unroll
            for (int j = 0; j < 8; ++j)
                wr[s * 8 + j] = W_hr[p * 64 + s * 32 + g4 * 8 + j];
        #pragma unroll
        for (int t4 = 0; t4 < 4; ++t4) {
            const float whh = W_hh[(t4 * 64 + w * 16 + ln) * 49 + p];
            #pragma unroll
            for (int i = 0; i < 16; ++i) Msum[t4][i] += whh * wr[i];
        }
    }

    // Resident B fragments with log2e factors folded in
    bf16x8 Bf[4][3];
    union U { unsigned int d[4]; bf16x8 v; };
    #pragma unroll
    for (int t4 = 0; t4 < 4; ++t4) {
        const float fac = (t4 == 2) ? 2.0f * LOG2E : -LOG2E;
        #pragma unroll
        for (int s = 0; s < 2; ++s) {
            U u;
            #pragma unroll
            for (int jj = 0; jj < 4; ++jj) {
                const unsigned int e0 = f2bf(fac * Msum[t4][s * 8 + 2 * jj]);
                const unsigned int e1 = f2bf(fac * Msum[t4][s * 8 + 2 * jj + 1]);
                u.d[jj] = e0 | (e1 << 16);
            }
            Bf[t4][s] = u.v;
        }
        U u; u.d[0] = u.d[1] = u.d[2] = u.d[3] = 0u;
        const int n = t4 * 64 + w * 16 + ln;
        if (g4 == 0) {                          // slots 64..71: x hi/lo pairs
            #pragma unroll
            for (int c4 = 0; c4 < 4; ++c4) {
                const unsigned int us = f2bf(fac * W_ih[n * 4 + c4]);
                u.d[c4] = us | (us << 16);
            }
        } else if (g4 == 1) {                   // slot 72: bias
            u.d[0] = f2bf(fac * (b_ih[n] + b_hh[n]));
        }
        Bf[t4][2] = u.v;
    }

    // Xbuf static part: constant-1 bias column (row byte 16), every step-slot.
    {
        const int tt0 = tid >> 4, row = tid & 15;
        const int byte = tt0 * XSLOTB + (((row * 64) + 16) ^ ((row & 7) << 4));
        *(unsigned int*)(Xbuf + byte) = 0x3F80u;        // bf16(1.0), lo = 0
    }

    // x chunk ownership: thread -> (batch bl, step-in-chunk xtt, comp)
    const int xbl = tid >> 6, xtt = (tid >> 2) & 15, xcomp = tid & 3;
    const int xrow = xbl * 4;
    const int xwb  = xtt * XSLOTB +
                     (((xrow * 64) + (xcomp * 4)) ^ ((xrow & 7) << 4));
    const long xgbase = ((long)(b0 + xbl) * TSTEPS) * 4 + xcomp;
    float xreg = x[xgbase + xtt * 4];                    // chunk 0 value
    __syncthreads();

    // Hoisted addresses (Abuf swizzle: ^((r&7)<<4) ^ ((r&8)<<2)), XOR-toggled dbuf
    const int axor = ((ln & 7) << 4) ^ ((ln & 8) << 2);
    int aoff0 = ((ln * AROWB) + (g4 * 16)) ^ axor;           // read buf 0 first
    int aoff1 = ((ln * AROWB) + 64 + (g4 * 16)) ^ axor;
    const int xroff = ((ln * 64) + (g4 * 16)) ^ ((ln & 7) << 4);
    const int wrow  = g4 * 4;                // this lane's valid C row (r=0)
    int woffp = (((wrow * AROWB) + 2 * (w * 16 + ln)) ^
                 (((wrow & 7) << 4) ^ ((wrow & 8) << 2))) ^ ABYTES;  // write buf 1 first

    const f32x4 ZV = {0.f, 0.f, 0.f, 0.f};   // loop-invariant zero C-in

    float cst = 0.f;
    float hffin = 0.f;
    int xrcur = xroff;

    // ---------------- recurrence ----------------
    for (int t = 0; t < TSTEPS; ++t) {
        if ((t & 15) == 0) {
            // publish this chunk's x (prefetched 16 steps ago), then prefetch next
            *(unsigned int*)(Xbuf + xwb) = split_pack(xreg);
            __syncthreads();
            const int nc = ((t >> 4) + 1 < 32) ? (t >> 4) + 1 : 31;
            xreg = x[xgbase + (nc * 16 + xtt) * 4];
            xrcur = xroff;
        }

        const bf16x8 af0 = *(const bf16x8*)(Abuf + aoff0);
        const bf16x8 af1 = *(const bf16x8*)(Abuf + aoff1);
        const bf16x8 af2 = *(const bf16x8*)(Xbuf + xrcur);
        xrcur += XSLOTB;

        f32x4 aI, aF, aG, aO;
        aI = __builtin_amdgcn_mfma_f32_16x16x32_bf16(af0, Bf[0][0], ZV, 0, 0, 0);
        aF = __builtin_amdgcn_mfma_f32_16x16x32_bf16(af0, Bf[1][0], ZV, 0, 0, 0);
        aG = __builtin_amdgcn_mfma_f32_16x16x32_bf16(af0, Bf[2][0], ZV, 0, 0, 0);
        aO = __builtin_amdgcn_mfma_f32_16x16x32_bf16(af0, Bf[3][0], ZV, 0, 0, 0);
        aI = __builtin_amdgcn_mfma_f32_16x16x32_bf16(af1, Bf[0][1], aI, 0, 0, 0);
        aF = __builtin_amdgcn_mfma_f32_16x16x32_bf16(af1, Bf[1][1], aF, 0, 0, 0);
        aG = __builtin_amdgcn_mfma_f32_16x16x32_bf16(af1, Bf[2][1], aG, 0, 0, 0);
        aO = __builtin_amdgcn_mfma_f32_16x16x32_bf16(af1, Bf[3][1], aO, 0, 0, 0);
        aI = __builtin_amdgcn_mfma_f32_16x16x32_bf16(af2, Bf[0][2], aI, 0, 0, 0);
        aF = __builtin_amdgcn_mfma_f32_16x16x32_bf16(af2, Bf[1][2], aF, 0, 0, 0);
        aG = __builtin_amdgcn_mfma_f32_16x16x32_bf16(af2, Bf[2][2], aG, 0, 0, 0);
        aO = __builtin_amdgcn_mfma_f32_16x16x32_bf16(af2, Bf[3][2], aO, 0, 0, 0);

        {
            const float gi = rcp1p(__builtin_amdgcn_exp2f(aI[0]));
            const float gf = rcp1p(__builtin_amdgcn_exp2f(aF[0]));
            const float rg = rcp1p(__builtin_amdgcn_exp2f(aG[0]));
            const float gg = fmaf(-2.0f, rg, 1.0f);
            const float go = rcp1p(__builtin_amdgcn_exp2f(aO[0]));
            cst = fmaf(gf, cst, gi * gg);
            const float rc = rcp1p(__builtin_amdgcn_exp2f(cst * (2.0f * LOG2E)));
            const float hf = go * fmaf(-2.0f, rc, 1.0f);
            hffin = hf;
            unsigned int pk;
            asm("v_cvt_pk_bf16_f32 %0, %1, %2" : "=v"(pk) : "v"(hf), "v"(0.0f));
            *(unsigned short*)(Abuf + woffp) = (unsigned short)pk;
        }

        __syncthreads();
        aoff0 ^= ABYTES; aoff1 ^= ABYTES; woffp ^= ABYTES;
    }

    // ---------------- epilogue (exact fp32 two-stage) ----------------
    hf32[g4][w * 16 + ln] = hffin;
    __syncthreads();

    for (int idx = tid; idx < BPB * 49; idx += 256) {
        const int bb = idx / 49, q = idx - bb * 49;
        float s = 0.0f;
        #pragma unroll 8
        for (int h = 0; h < 64; ++h) s += hf32[bb][h] * W_hr[q * 64 + h];
        hproj[bb][q] = s;
    }
    __syncthreads();
    for (int idx = tid; idx < BPB * 49; idx += 256) {
        const int bb = idx / 49, q2 = idx - bb * 49;
        float s = b_out[q2];
        #pragma unroll 7
        for (int p = 0; p < 49; ++p) s += hproj[bb][p] * W_out[q2 * 49 + p];
        out[(b0 + bb) * 49 + q2] = s;
    }
}

extern "C" void kernel_launch(void* const* d_in, const int* in_sizes, int n_in,
                              void* d_out, int out_size, void* d_ws, size_t ws_size,
                              hipStream_t stream) {
    (void)in_sizes; (void)n_in; (void)d_ws; (void)ws_size; (void)out_size;
    const float* x     = (const float*)d_in[0];
    const float* W_ih  = (const float*)d_in[1];
    const float* W_hh  = (const float*)d_in[2];
    const float* b_ih  = (const float*)d_in[3];
    const float* b_hh  = (const float*)d_in[4];
    const float* W_hr  = (const float*)d_in[5];
    const float* W_out = (const float*)d_in[6];
    const float* b_out = (const float*)d_in[7];
    float* outp = (float*)d_out;

    lstm_mfma13_kernel<<<dim3(2048 / BPB), dim3(256), 0, stream>>>(
        x, W_ih, W_hh, b_ih, b_hh, W_hr, W_out, b_out, outp);
}